// Round 1
// baseline (59.256 us; speedup 1.0000x reference)
//
#include <hip/hip_runtime.h>

// PS-RoI-Align (matches torchvision.ops.ps_roi_align semantics per reference).
// feat: [N=4, C=784, H=112, W=112] fp32; rois: [K,5] fp32; out: [K, 16, 7, 7] fp32.
// C = Cout*P*P with P=7, Cout=16. SCALE=1/16, SR=2 sampling grid, mean over 4 samples.

#define PP 7
#define SR 2
#define SCALEF 0.0625f

constexpr int Nn   = 4;
constexpr int Cc   = 784;
constexpr int Hh   = 112;
constexpr int Ww   = 112;
constexpr int Cout = 16;

__global__ __launch_bounds__(256) void psroi_align_kernel(
    const float* __restrict__ feat,
    const float* __restrict__ rois,
    float* __restrict__ out,
    int total)
{
    int idx = blockIdx.x * 256 + threadIdx.x;
    if (idx >= total) return;

    // out layout: [K, Cout, P, P] flat
    int pw = idx % PP;
    int t  = idx / PP;
    int ph = t % PP;
    t /= PP;
    int cout = t % Cout;
    int k    = t / Cout;

    const float* r = rois + (size_t)k * 5;
    int   b  = (int)r[0];
    float x1 = r[1] * SCALEF - 0.5f;
    float y1 = r[2] * SCALEF - 0.5f;
    float x2 = r[3] * SCALEF - 0.5f;
    float y2 = r[4] * SCALEF - 0.5f;
    float roi_w = fmaxf(x2 - x1, 0.1f);
    float roi_h = fmaxf(y2 - y1, 0.1f);
    float bsh = roi_h / (float)PP;
    float bsw = roi_w / (float)PP;

    // position-sensitive channel
    int c = cout * (PP * PP) + ph * PP + pw;
    const float* f = feat + ((size_t)b * Cc + (size_t)c) * (size_t)(Hh * Ww);

    float acc = 0.0f;
#pragma unroll
    for (int iy = 0; iy < SR; ++iy) {
        float gy = ((float)iy + 0.5f) / (float)SR;
        float y  = y1 + ((float)ph + gy) * bsh;
        bool  vy = (y >= -1.0f) && (y <= (float)Hh);
        float yc = fminf(fmaxf(y, 0.0f), (float)(Hh - 1));
        int   yl = (int)floorf(yc);
        int   yh = min(yl + 1, Hh - 1);
        float ly = yc - (float)yl;
        float hy = 1.0f - ly;
#pragma unroll
        for (int ix = 0; ix < SR; ++ix) {
            float gx = ((float)ix + 0.5f) / (float)SR;
            float x  = x1 + ((float)pw + gx) * bsw;
            bool  vx = (x >= -1.0f) && (x <= (float)Ww);
            float xc = fminf(fmaxf(x, 0.0f), (float)(Ww - 1));
            int   xl = (int)floorf(xc);
            int   xh = min(xl + 1, Ww - 1);
            float lx = xc - (float)xl;
            float hx = 1.0f - lx;

            float v = hy * hx * f[yl * Ww + xl]
                    + hy * lx * f[yl * Ww + xh]
                    + ly * hx * f[yh * Ww + xl]
                    + ly * lx * f[yh * Ww + xh];
            acc += (vy && vx) ? v : 0.0f;
        }
    }
    out[idx] = acc * (1.0f / (float)(SR * SR));
}

extern "C" void kernel_launch(void* const* d_in, const int* in_sizes, int n_in,
                              void* d_out, int out_size, void* d_ws, size_t ws_size,
                              hipStream_t stream) {
    const float* feat = (const float*)d_in[0];
    const float* rois = (const float*)d_in[1];
    float* out = (float*)d_out;

    int K = in_sizes[1] / 5;
    int total = K * Cout * PP * PP;   // == out_size
    int blocks = (total + 255) / 256;
    psroi_align_kernel<<<blocks, 256, 0, stream>>>(feat, rois, out, total);
}